// Round 22
// baseline (689.997 us; speedup 1.0000x reference)
//
#include <hip/hip_runtime.h>

#define BT 32768
#define CDIM 512
#define KCB 1024
#define NQ 4
#define IDX_BASE (BT*CDIM)
#define LOSS_OFF (BT*CDIM + BT*NQ)
#define CAND_MAX 64
#define MARGIN_C 0.0025f
#define MARGIN_A 0.004f

// ws byte offsets
#define WS_LIST   256
#define WS_A2     (WS_LIST + BT*4)
#define WS_B2     (WS_A2 + BT*4)
#define WS_RBC    (WS_B2 + NQ*KCB*4)
#define WS_CBB    (WS_RBC + BT*CDIM*2)
#define WS_CCNT   (WS_CBB + NQ*KCB*CDIM*2)
#define WS_CANDK  (WS_CCNT + BT*4)
#define WS_CANDS  (WS_CANDK + BT*CAND_MAX*4)
#define WS_IDXS   (WS_CANDS + BT*CAND_MAX*4)

typedef __attribute__((ext_vector_type(8))) _Float16 f16x8;
typedef __attribute__((ext_vector_type(4))) float f32x4;

// fp32 -> fp16 RNE (IEEE cast), returned as uint for packing
__device__ __forceinline__ unsigned int f2h(float f) {
  union { _Float16 h; unsigned short u; } cv;
  cv.h = (_Float16)f;
  return (unsigned int)cv.u;
}

// position of (n+1)-th set bit of m (n < popcount(m))
__device__ __forceinline__ int nth_bit(unsigned long long m, int n) {
  int pos = 0;
#pragma unroll
  for (int w = 32; w >= 1; w >>= 1) {
    unsigned long long lowmask = (w == 64) ? ~0ull : ((1ull << w) - 1ull);
    int c = __popcll(m & lowmask);
    if (n >= c) { n -= c; m >>= w; pos += w; }
  }
  return pos;
}

// Exact sequential-c single-accumulator FMA chain, 8-deep register pipeline.
// FP order byte-identical to the reference chain. Rare path only (~7%).
__device__ __forceinline__ float chain512q(const float* lds_r, const float* brow) {
  const float4* b4 = (const float4*)brow;
  float4 cur[8], nxt[8];
#pragma unroll
  for (int q = 0; q < 8; ++q) cur[q] = b4[q];
  float ab = 0.f;
#pragma unroll 1
  for (int seg = 0; seg < 15; ++seg) {
#pragma unroll
    for (int q = 0; q < 8; ++q) nxt[q] = b4[(seg + 1) * 8 + q];
#pragma unroll
    for (int q = 0; q < 8; ++q) {
      float4 bv = cur[q];
      float4 rv = *(const float4*)&lds_r[(seg * 8 + q) * 4];  // LDS broadcast
      ab = __fmaf_rn(rv.x, bv.x, ab);
      ab = __fmaf_rn(rv.y, bv.y, ab);
      ab = __fmaf_rn(rv.z, bv.z, ab);
      ab = __fmaf_rn(rv.w, bv.w, ab);
    }
#pragma unroll
    for (int q = 0; q < 8; ++q) cur[q] = nxt[q];
  }
#pragma unroll
  for (int q = 0; q < 8; ++q) {
    float4 bv = cur[q];
    float4 rv = *(const float4*)&lds_r[(120 + q) * 4];
    ab = __fmaf_rn(rv.x, bv.x, ab);
    ab = __fmaf_rn(rv.y, bv.y, ab);
    ab = __fmaf_rn(rv.z, bv.z, ab);
    ab = __fmaf_rn(rv.w, bv.w, ab);
  }
  return ab;
}

// mask storage formats: 0=u8, 1=i32, 2=i64, 3=bf16, 4=f32
__device__ __forceinline__ int mask_at(const void* m, int t, int flag) {
  switch (flag) {
    case 0:  return ((const unsigned char*)m)[t] != 0;
    case 1:  return ((const int*)m)[t] != 0;
    case 2:  return ((const unsigned long long*)m)[t] != 0ull;
    case 3:  return ((const unsigned short*)m)[t] != 0;
    default: return ((const float*)m)[t] != 0.0f;
  }
}

// Detect mask format, count n_valid, build order-preserving compacted list.
__global__ void k_prep(const unsigned char* mask, int* wsi, float* wsf, int* list) {
  __shared__ int s_not01, s_off1, s_offn0, s_odd, s_fm;
  __shared__ int s_cnt[1024];
  int tid = threadIdx.x;
  if (tid == 0) { s_not01 = 0; s_off1 = 0; s_offn0 = 0; s_odd = 0; }
  __syncthreads();
  int l_not01 = 0, l_off1 = 0, l_offn0 = 0, l_odd = 0;
  for (int o = tid; o < BT; o += 1024) {
    unsigned char b = mask[o];
    if (b) {
      if (b > 1) l_not01 = 1;
      int m4 = o & 3;
      if (m4 == 1) l_off1 = 1;
      if (m4) l_offn0 = 1;
      if ((o & 7) >= 4) l_odd = 1;
    }
  }
  if (l_not01) atomicOr(&s_not01, 1);
  if (l_off1)  atomicOr(&s_off1, 1);
  if (l_offn0) atomicOr(&s_offn0, 1);
  if (l_odd)   atomicOr(&s_odd, 1);
  __syncthreads();
  if (tid == 0) {
    int fm;
    if (s_not01)      fm = s_off1 ? 3 : 4;
    else if (s_offn0) fm = 0;
    else if (s_odd)   fm = 1;
    else              fm = 2;
    s_fm = fm; wsi[0] = fm;
    wsf[8] = 0.0f;                       // loss accumulator
    wsf[12] = 0.f; wsf[13] = 0.f; wsf[14] = 0.f; wsf[15] = 0.f;  // b2max
  }
  __syncthreads();
  int fm = s_fm;
  int base = tid * 32, cnt = 0;
  for (int u = 0; u < 32; u++) cnt += mask_at(mask, base + u, fm);
  int val = cnt;
  s_cnt[tid] = val;
  __syncthreads();
#pragma unroll
  for (int off = 1; off < 1024; off <<= 1) {
    int v = (tid >= off) ? s_cnt[tid - off] : 0;
    __syncthreads();
    val += v;
    s_cnt[tid] = val;
    __syncthreads();
  }
  if (tid == 0) wsi[2] = s_cnt[1023];
  int woff = val - cnt;                  // exclusive prefix
  for (int u = 0; u < 32; u++) {
    int t = base + u;
    if (mask_at(mask, t, fm)) list[woff++] = t;
  }
}

// Invalid tokens: x_q row = 0, indices = -1.
__global__ void k_fill(const void* mask, float* out, const int* wsi) {
  int w = threadIdx.x >> 6, lane = threadIdx.x & 63;
  int t = blockIdx.x * 4 + w;
  if (t >= BT) return;
  if (mask_at(mask, t, wsi[0])) return;
  float4 z = make_float4(0.f, 0.f, 0.f, 0.f);
  float4* p = (float4*)(out + (size_t)t * CDIM) + lane * 2;
  p[0] = z; p[1] = z;
  if (lane < NQ) out[IDX_BASE + (size_t)t * NQ + lane] = -1.0f;
}

// b2: exact sequential chain (one chain per WAVE, not all on wave 0).
__global__ void k_b2(const float* __restrict__ cb, float* __restrict__ b2, float* b2max) {
  __shared__ float st[4][512];
  int w = threadIdx.x >> 6, lane = threadIdx.x & 63;
  int row = blockIdx.x * 4 + w;
  const float4* p = (const float4*)(cb + (size_t)row * CDIM) + lane * 2;
  float4 v0 = p[0], v1 = p[1];
  *(float4*)&st[w][lane * 8] = v0;
  *(float4*)&st[w][lane * 8 + 4] = v1;
  __syncthreads();
  if ((threadIdx.x & 63) == 0) {         // lane 0 of each wave: 1 chain/wave
    int r2 = blockIdx.x * 4 + w;
    float s = 0.f;
    for (int c4 = 0; c4 < 128; ++c4) {
      float4 v = *(float4*)&st[w][c4 * 4];
      s = __fadd_rn(s, __fmul_rn(v.x, v.x));
      s = __fadd_rn(s, __fmul_rn(v.y, v.y));
      s = __fadd_rn(s, __fmul_rn(v.z, v.z));
      s = __fadd_rn(s, __fmul_rn(v.w, v.w));
    }
    b2[r2] = s;
    atomicMax((int*)&b2max[r2 >> 10], __float_as_int(s));
  }
}

// cb -> fp16 (RNE), once for all codebooks.
__global__ void k_cvtcb(const float* __restrict__ cb, unsigned short* __restrict__ cbb) {
  size_t i = (size_t)blockIdx.x * blockDim.x + threadIdx.x;
  const float4* s = (const float4*)(cb + i * 8);
  float4 a = s[0], b = s[1];
  uint4 u;
  u.x = f2h(a.x) | (f2h(a.y) << 16);
  u.y = f2h(a.z) | (f2h(a.w) << 16);
  u.z = f2h(b.x) | (f2h(b.y) << 16);
  u.w = f2h(b.z) | (f2h(b.w) << 16);
  *(uint4*)(cbb + i * 8) = u;
}

// rws[t] = x[t]; rbc[j] = fp16(x[t]); a2c[j] = exact sequential chain
// (2 chains per wave via lane-0-of-each-32-group, not 8 chains on wave 0).
__global__ __launch_bounds__(256) void k_init(const float* __restrict__ x,
    float* __restrict__ rws, unsigned short* __restrict__ rbc,
    const int* __restrict__ wsi, const int* __restrict__ list,
    float* __restrict__ a2c, int* __restrict__ candcnt) {
  __shared__ float st[8][512];
  int nv = wsi[2];
  int j0 = blockIdx.x * 8;
  int tid = threadIdx.x;
  if (tid < 8) candcnt[j0 + tid] = 0;
  if (j0 >= nv) return;
  int slot = tid >> 5;
  int j = j0 + slot;
  int c0 = (tid & 31) * 16;
  if (j < nv) {
    int t = list[j];
    const float4* src = (const float4*)(x + (size_t)t * CDIM + c0);
    float4* dst = (float4*)(rws + (size_t)t * CDIM + c0);
    float4 v0 = src[0], v1 = src[1], v2 = src[2], v3 = src[3];
    dst[0] = v0; dst[1] = v1; dst[2] = v2; dst[3] = v3;
    *(float4*)&st[slot][c0]      = v0; *(float4*)&st[slot][c0 + 4]  = v1;
    *(float4*)&st[slot][c0 + 8]  = v2; *(float4*)&st[slot][c0 + 12] = v3;
    uint4 u0, u1;
    u0.x = f2h(v0.x) | (f2h(v0.y) << 16); u0.y = f2h(v0.z) | (f2h(v0.w) << 16);
    u0.z = f2h(v1.x) | (f2h(v1.y) << 16); u0.w = f2h(v1.z) | (f2h(v1.w) << 16);
    u1.x = f2h(v2.x) | (f2h(v2.y) << 16); u1.y = f2h(v2.z) | (f2h(v2.w) << 16);
    u1.z = f2h(v3.x) | (f2h(v3.y) << 16); u1.w = f2h(v3.z) | (f2h(v3.w) << 16);
    uint4* bd = (uint4*)(rbc + (size_t)j * CDIM + c0);
    bd[0] = u0; bd[1] = u1;
  }
  __syncthreads();
  if ((tid & 31) == 0) {                 // slot's own group-leader: 2 chains/wave
    int jj = j0 + slot;
    if (jj < nv) {
      float s = 0.f;
      for (int c4 = 0; c4 < 128; ++c4) {
        float4 v = *(float4*)&st[slot][c4 * 4];
        s = __fadd_rn(s, __fmul_rn(v.x, v.x));
        s = __fadd_rn(s, __fmul_rn(v.y, v.y));
        s = __fadd_rn(s, __fmul_rn(v.z, v.z));
        s = __fadd_rn(s, __fmul_rn(v.w, v.w));
      }
      a2c[jj] = s;
    }
  }
}

// fp16 MFMA GEMM: M-tile 64 (2048 real blocks, 8/CU -> phases overlap across
// blocks), 24KB LDS, DMA staging + bijective runtime-sized XCD remap.
__global__ __launch_bounds__(256) void k_gemm(const unsigned short* __restrict__ rbc,
    const unsigned short* __restrict__ cbb, const float* __restrict__ b2,
    const float* __restrict__ b2max, const float* __restrict__ a2c,
    const int* __restrict__ wsi, int* __restrict__ candcnt,
    int* __restrict__ candk, float* __restrict__ cands, int ic) {
  __shared__ __align__(16) unsigned short As[64 * 64];
  __shared__ __align__(16) unsigned short Bs[128 * 64];
  int nv = wsi[2];
  int nmb = (nv + 63) >> 6;             // real mb count (M-tile = 64)
  int q = blockIdx.x >> 3, x = blockIdx.x & 7;
  if (q >= nmb) return;                 // balanced early-exit across XCDs
  int r = x * nmb + q;                  // bijective: XCD x owns works x*nmb..
  int mb = r >> 3, nb = r & 7;
  int m0 = mb * 64;
  if (m0 >= nv) return;
  int tid = threadIdx.x;
  int w = tid >> 6, lane = tid & 63;
  int wm = w >> 1, wn = w & 1;
  f32x4 acc[2][4];
#pragma unroll
  for (int a = 0; a < 2; a++)
#pragma unroll
    for (int b = 0; b < 4; b++) acc[a][b] = (f32x4){0.f, 0.f, 0.f, 0.f};

  const unsigned short* Ag = rbc + (size_t)m0 * CDIM;
  const unsigned short* Bg = cbb + (size_t)(ic * KCB + nb * 128) * CDIM;
  int w4 = __builtin_amdgcn_readfirstlane(w);   // wave id, scalar
  int lr8 = lane >> 3, lck = lane & 7;
  int l15 = lane & 15, l4 = lane >> 4;

  for (int kc = 0; kc < 8; ++kc) {
    __syncthreads();                    // prev iteration's reads complete
#pragma unroll
    for (int i = 0; i < 2; ++i) {       // A: 64 rows, 16/wave
      int ra = w4 * 16 + i * 8 + lr8;
      int sc = (lck ^ (ra & 7)) << 3;
      const unsigned short* sa = Ag + (size_t)ra * CDIM + kc * 64 + sc;
      __builtin_amdgcn_global_load_lds(
          (const __attribute__((address_space(1))) unsigned int*)sa,
          (__attribute__((address_space(3))) unsigned int*)&As[(w4 * 16 + i * 8) * 64],
          16, 0, 0);
    }
#pragma unroll
    for (int i = 0; i < 4; ++i) {       // B: 128 rows, 32/wave
      int rb_ = w4 * 32 + i * 8 + lr8;
      int sc = (lck ^ (rb_ & 7)) << 3;
      const unsigned short* sb = Bg + (size_t)rb_ * CDIM + kc * 64 + sc;
      __builtin_amdgcn_global_load_lds(
          (const __attribute__((address_space(1))) unsigned int*)sb,
          (__attribute__((address_space(3))) unsigned int*)&Bs[(w4 * 32 + i * 8) * 64],
          16, 0, 0);
    }
    asm volatile("s_waitcnt vmcnt(0)" ::: "memory");
    __syncthreads();
#pragma unroll
    for (int h = 0; h < 2; ++h) {
      f16x8 af[2], bf[4];
#pragma unroll
      for (int mf = 0; mf < 2; ++mf) {
        int row = wm * 32 + mf * 16 + l15;
        af[mf] = *(const f16x8*)&As[row * 64 + (((h * 4 + l4) ^ (row & 7)) << 3)];
      }
#pragma unroll
      for (int nf = 0; nf < 4; ++nf) {
        int row = wn * 64 + nf * 16 + l15;
        bf[nf] = *(const f16x8*)&Bs[row * 64 + (((h * 4 + l4) ^ (row & 7)) << 3)];
      }
#pragma unroll
      for (int mf = 0; mf < 2; ++mf)
#pragma unroll
        for (int nf = 0; nf < 4; ++nf)
          acc[mf][nf] = __builtin_amdgcn_mfma_f32_16x16x32_f16(af[mf], bf[nf], acc[mf][nf], 0, 0, 0);
    }
  }

  const float* b2p = b2 + ic * KCB;
  float bmax = b2max[ic];
#pragma unroll
  for (int mf = 0; mf < 2; ++mf) {
    float sv[4][4];
    int kg[4];
    float smin[4]; int kmin[4];
#pragma unroll
    for (int q2 = 0; q2 < 4; ++q2) { smin[q2] = __builtin_inff(); kmin[q2] = 0; }
#pragma unroll
    for (int nf = 0; nf < 4; ++nf) {
      int k = nb * 128 + wn * 64 + nf * 16 + l15;
      kg[nf] = k;
      float b2k = b2p[k];
#pragma unroll
      for (int q2 = 0; q2 < 4; ++q2) {
        float s = __fsub_rn(b2k, __fmul_rn(2.0f, acc[mf][nf][q2]));
        sv[nf][q2] = s;
        if (s < smin[q2]) { smin[q2] = s; kmin[q2] = k; }
      }
    }
#pragma unroll
    for (int d = 1; d < 16; d <<= 1) {
#pragma unroll
      for (int q2 = 0; q2 < 4; ++q2) {
        float vo = __shfl_xor(smin[q2], d, 64);
        int ko = __shfl_xor(kmin[q2], d, 64);
        if (vo < smin[q2] || (vo == smin[q2] && ko < kmin[q2])) { smin[q2] = vo; kmin[q2] = ko; }
      }
    }
#pragma unroll
    for (int q2 = 0; q2 < 4; ++q2) {
      int j = m0 + wm * 32 + mf * 16 + l4 * 4 + q2;
      if (j < nv) {
        float thr = smin[q2] + MARGIN_C * sqrtf(a2c[j] * bmax) + MARGIN_A;
#pragma unroll
        for (int nf = 0; nf < 4; ++nf) {
          if (sv[nf][q2] <= thr) {
            int pos = atomicAdd(&candcnt[j], 1);
            if (pos < CAND_MAX) {
              candk[(size_t)j * CAND_MAX + pos] = kg[nf];
              cands[(size_t)j * CAND_MAX + pos] = sv[nf][q2];
            }
          }
        }
      }
    }
  }
}

// Argmin only. One token per wave. nk==1 (~93% with fp16 margin) -> free.
__global__ __launch_bounds__(256) void k_argmin(const float* __restrict__ cb,
    const float* __restrict__ rws, const int* __restrict__ list,
    const int* __restrict__ wsi, const float* __restrict__ a2c,
    const float* __restrict__ b2, const float* __restrict__ b2max,
    int* __restrict__ candcnt, const int* __restrict__ candk,
    const float* __restrict__ cands, float* __restrict__ out,
    int* __restrict__ idxsel, int ic) {
  __shared__ float rbuf[4][512];
  int nv = wsi[2];
  int tid = threadIdx.x, wv = tid >> 6, lane = tid & 63;
  int j = blockIdx.x * 4 + wv;
  if (j >= nv) return;                 // per-wave exit; no block barriers
  int t = __builtin_amdgcn_readfirstlane(list[j]);
  int cnt = candcnt[j];
  if (lane == 0) candcnt[j] = 0;       // reset for next codebook
  float a2v = a2c[j];
  const float* b2p = b2 + ic * KCB;
  const float* cbp = cb + (size_t)ic * KCB * CDIM;

  int kw;
  if (cnt <= CAND_MAX) {
    float sa = __builtin_inff(); int kl = 0;
    if (lane < cnt) {
      sa = cands[(size_t)j * CAND_MAX + lane];
      kl = candk[(size_t)j * CAND_MAX + lane];
    }
    float g = sa;
#pragma unroll
    for (int d = 1; d < 64; d <<= 1) g = fminf(g, __shfl_xor(g, d, 64));
    float M = MARGIN_C * sqrtf(a2v * b2max[ic]) + MARGIN_A;
    bool keep = (lane < cnt) && (sa <= g + M);
    unsigned long long mkb = __ballot(keep);
    int nk = (int)__popcll(mkb);         // >= 1 always (min survives)
    if (nk == 1) {
      int src = nth_bit(mkb, 0);
      kw = __shfl(kl, src, 64);
    } else {
      const float4* rr = (const float4*)(rws + (size_t)t * CDIM);
      float4 r0 = rr[lane * 2], r1 = rr[lane * 2 + 1];
      *(float4*)&rbuf[wv][lane * 8]     = r0;
      *(float4*)&rbuf[wv][lane * 8 + 4] = r1;
      int sel = lane % nk;
      int src = nth_bit(mkb, sel);
      int myk = __shfl(kl, src, 64);
      asm volatile("s_waitcnt lgkmcnt(0)" ::: "memory");
      float ab = chain512q(rbuf[wv], cbp + (size_t)myk * CDIM);
      float dv = __fsub_rn(__fadd_rn(a2v, b2p[myk]), __fmul_rn(2.0f, ab));
      int kc = myk;
#pragma unroll
      for (int d = 1; d < 64; d <<= 1) {
        float vo = __shfl_xor(dv, d, 64);
        int ko = __shfl_xor(kc, d, 64);
        if (vo < dv || (vo == dv && ko < kc)) { dv = vo; kc = ko; }
      }
      kw = kc;
    }
  } else {
    // provable fallback: full exact scan, 64 rows per pass (rare)
    const float4* rr = (const float4*)(rws + (size_t)t * CDIM);
    float4 r0 = rr[lane * 2], r1 = rr[lane * 2 + 1];
    *(float4*)&rbuf[wv][lane * 8]     = r0;
    *(float4*)&rbuf[wv][lane * 8 + 4] = r1;
    asm volatile("s_waitcnt lgkmcnt(0)" ::: "memory");
    float dl = __builtin_inff(); int kl2 = 0x7fffffff;
    for (int base = 0; base < KCB; base += 64) {
      int myk = base + lane;
      float ab = chain512q(rbuf[wv], cbp + (size_t)myk * CDIM);
      float dv = __fsub_rn(__fadd_rn(a2v, b2p[myk]), __fmul_rn(2.0f, ab));
      if (dv < dl || (dv == dl && myk < kl2)) { dl = dv; kl2 = myk; }
    }
#pragma unroll
    for (int d = 1; d < 64; d <<= 1) {
      float vo = __shfl_xor(dl, d, 64);
      int ko = __shfl_xor(kl2, d, 64);
      if (vo < dl || (vo == dl && ko < kl2)) { dl = vo; kl2 = ko; }
    }
    kw = kl2;
  }
  if (lane == 0) {
    out[IDX_BASE + (size_t)t * NQ + ic] = (float)kw;
    idxsel[j] = kw;
  }
}

// Streaming exact residual update: 8 tokens/block. a2 re-chains run on the
// group-leader lane of each token's own 32-thread group (2 chains/wave,
// 2-way-bank free) instead of all 8 on wave 0 (16K-cycle single-wave tail).
__global__ __launch_bounds__(256) void k_upd2(const float* __restrict__ x,
    const float* __restrict__ cb, float* __restrict__ rws,
    unsigned short* __restrict__ rbc, const int* __restrict__ list,
    const int* __restrict__ wsi, float* __restrict__ a2c,
    const int* __restrict__ idxsel, float* __restrict__ lossacc, int ic) {
  __shared__ float st[8][512];
  __shared__ float s_l[4];
  int nv = wsi[2];
  int j0 = blockIdx.x * 8;
  if (j0 >= nv) return;
  int tid = threadIdx.x;
  int slot = tid >> 5;
  int j = j0 + slot;
  bool valid = (j < nv);
  int jc = valid ? j : (nv - 1);
  int t = list[jc];
  int kw = idxsel[jc];
  int c0 = (tid & 31) * 16;
  const float* cbp = cb + (size_t)ic * KCB * CDIM;
  float lsum = 0.f;
  if (valid) {
    float4* rp = (float4*)(rws + (size_t)t * CDIM + c0);
    const float4* qp = (const float4*)(cbp + (size_t)kw * CDIM + c0);
#pragma unroll
    for (int q4 = 0; q4 < 4; ++q4) {
      float4 rv = rp[q4], qv = qp[q4];
      float4 d, n;
      d.x = __fsub_rn(qv.x, rv.x); d.y = __fsub_rn(qv.y, rv.y);
      d.z = __fsub_rn(qv.z, rv.z); d.w = __fsub_rn(qv.w, rv.w);
      n.x = __fsub_rn(rv.x, __fadd_rn(rv.x, d.x));
      n.y = __fsub_rn(rv.y, __fadd_rn(rv.y, d.y));
      n.z = __fsub_rn(rv.z, __fadd_rn(rv.z, d.z));
      n.w = __fsub_rn(rv.w, __fadd_rn(rv.w, d.w));
      lsum = __fmaf_rn(d.x, d.x, lsum); lsum = __fmaf_rn(d.y, d.y, lsum);
      lsum = __fmaf_rn(d.z, d.z, lsum); lsum = __fmaf_rn(d.w, d.w, lsum);
      if (ic < 3) {
        rp[q4] = n;
        *(float4*)&st[slot][c0 + q4 * 4] = n;
        uint2 u;
        u.x = f2h(n.x) | (f2h(n.y) << 16);
        u.y = f2h(n.z) | (f2h(n.w) << 16);
        *(uint2*)(rbc + (size_t)j * CDIM + c0 + q4 * 4) = u;
      } else {
        float4 xv = ((const float4*)(x + (size_t)t * CDIM + c0))[q4];
        float4 o;
        o.x = __fsub_rn(xv.x, n.x); o.y = __fsub_rn(xv.y, n.y);
        o.z = __fsub_rn(xv.z, n.z); o.w = __fsub_rn(xv.w, n.w);
        rp[q4] = o;                 // rws row == out x_q row
      }
    }
  }
  // loss: wave reduce -> LDS -> one atomic
#pragma unroll
  for (int d = 1; d < 64; d <<= 1) lsum += __shfl_xor(lsum, d, 64);
  if ((tid & 63) == 0) s_l[tid >> 6] = lsum;
  __syncthreads();
  if (ic < 3 && (tid & 31) == 0) {       // slot's group-leader: 2 chains/wave
    int jj = j0 + slot;
    if (jj < nv) {
      float s = 0.f;
      for (int c4 = 0; c4 < 128; ++c4) {
        float4 v = *(float4*)&st[slot][c4 * 4];
        s = __fadd_rn(s, __fmul_rn(v.x, v.x));
        s = __fadd_rn(s, __fmul_rn(v.y, v.y));
        s = __fadd_rn(s, __fmul_rn(v.z, v.z));
        s = __fadd_rn(s, __fmul_rn(v.w, v.w));
      }
      a2c[jj] = s;
    }
  }
  if (tid == 0) atomicAdd(lossacc, (s_l[0] + s_l[1]) + (s_l[2] + s_l[3]));
}

__global__ void k_loss(const int* wsi, const float* acc, float* out) {
  if (threadIdx.x == 0 && blockIdx.x == 0) {
    float n = (float)wsi[2];
    if (n < 1.0f) n = 1.0f;
    out[LOSS_OFF] = acc[0] * 1.25f / (n * (float)CDIM);
  }
}

extern "C" void kernel_launch(void* const* d_in, const int* in_sizes, int n_in,
                              void* d_out, int out_size, void* d_ws, size_t ws_size,
                              hipStream_t stream) {
  const float* x   = (const float*)d_in[0];
  const void* mask = d_in[1];
  const float* cb  = (const float*)d_in[2];
  float* out = (float*)d_out;
  char* ws = (char*)d_ws;
  int*   wsi  = (int*)ws;
  float* wsf  = (float*)ws;
  int*   list = (int*)(ws + WS_LIST);
  float* a2c  = (float*)(ws + WS_A2);
  float* b2   = (float*)(ws + WS_B2);
  unsigned short* rbc = (unsigned short*)(ws + WS_RBC);
  unsigned short* cbb = (unsigned short*)(ws + WS_CBB);
  int*   ccnt = (int*)(ws + WS_CCNT);
  int*   ck   = (int*)(ws + WS_CANDK);
  float* cs   = (float*)(ws + WS_CANDS);
  int*   isel = (int*)(ws + WS_IDXS);
  float* rws  = out;            // x_q region doubles as residual ws (token rows)
  float* b2mx = wsf + 12;

  hipLaunchKernelGGL(k_prep, dim3(1), dim3(1024), 0, stream,
                     (const unsigned char*)mask, wsi, wsf, list);
  hipLaunchKernelGGL(k_fill, dim3(BT / 4), dim3(256), 0, stream, mask, out, wsi);
  hipLaunchKernelGGL(k_b2, dim3(NQ * KCB / 4), dim3(256), 0, stream, cb, b2, b2mx);
  hipLaunchKernelGGL(k_cvtcb, dim3(NQ * KCB * CDIM / 8 / 256), dim3(256), 0, stream, cb, cbb);
  hipLaunchKernelGGL(k_init, dim3(BT / 8), dim3(256), 0, stream,
                     x, rws, rbc, wsi, list, a2c, ccnt);
  for (int ic = 0; ic < NQ; ic++) {
    hipLaunchKernelGGL(k_gemm, dim3((BT / 64) * 8), dim3(256), 0, stream,
                       rbc, cbb, b2, b2mx, a2c, wsi, ccnt, ck, cs, ic);
    hipLaunchKernelGGL(k_argmin, dim3(BT / 4), dim3(256), 0, stream,
                       cb, rws, list, wsi, a2c, b2, b2mx, ccnt, ck, cs,
                       out, isel, ic);
    hipLaunchKernelGGL(k_upd2, dim3(BT / 8), dim3(256), 0, stream,
                       x, cb, rws, rbc, list, wsi, a2c, isel, wsf + 8, ic);
  }
  hipLaunchKernelGGL(k_loss, dim3(1), dim3(1), 0, stream, wsi, wsf + 8, out);
}

// Round 23
// 643.891 us; speedup vs baseline: 1.0716x; 1.0716x over previous
//
#include <hip/hip_runtime.h>

#define BT 32768
#define CDIM 512
#define KCB 1024
#define NQ 4
#define IDX_BASE (BT*CDIM)
#define LOSS_OFF (BT*CDIM + BT*NQ)
#define CAND_MAX 64
#define MARGIN_C 0.0025f
#define MARGIN_A 0.004f

// ws byte offsets
#define WS_LIST   256
#define WS_A2     (WS_LIST + BT*4)
#define WS_B2     (WS_A2 + BT*4)
#define WS_RBC    (WS_B2 + NQ*KCB*4)
#define WS_CBB    (WS_RBC + BT*CDIM*2)
#define WS_CCNT   (WS_CBB + NQ*KCB*CDIM*2)
#define WS_CANDK  (WS_CCNT + BT*4)
#define WS_CANDS  (WS_CANDK + BT*CAND_MAX*4)
#define WS_IDXS   (WS_CANDS + BT*CAND_MAX*4)

typedef __attribute__((ext_vector_type(8))) _Float16 f16x8;
typedef __attribute__((ext_vector_type(4))) float f32x4;

// fp32 -> fp16 RNE (IEEE cast), returned as uint for packing
__device__ __forceinline__ unsigned int f2h(float f) {
  union { _Float16 h; unsigned short u; } cv;
  cv.h = (_Float16)f;
  return (unsigned int)cv.u;
}

// position of (n+1)-th set bit of m (n < popcount(m))
__device__ __forceinline__ int nth_bit(unsigned long long m, int n) {
  int pos = 0;
#pragma unroll
  for (int w = 32; w >= 1; w >>= 1) {
    unsigned long long lowmask = (w == 64) ? ~0ull : ((1ull << w) - 1ull);
    int c = __popcll(m & lowmask);
    if (n >= c) { n -= c; m >>= w; pos += w; }
  }
  return pos;
}

// Exact sequential-c single-accumulator FMA chain, 8-deep register pipeline.
// FP order byte-identical to the reference chain. Rare path only (~7%).
__device__ __forceinline__ float chain512q(const float* lds_r, const float* brow) {
  const float4* b4 = (const float4*)brow;
  float4 cur[8], nxt[8];
#pragma unroll
  for (int q = 0; q < 8; ++q) cur[q] = b4[q];
  float ab = 0.f;
#pragma unroll 1
  for (int seg = 0; seg < 15; ++seg) {
#pragma unroll
    for (int q = 0; q < 8; ++q) nxt[q] = b4[(seg + 1) * 8 + q];
#pragma unroll
    for (int q = 0; q < 8; ++q) {
      float4 bv = cur[q];
      float4 rv = *(const float4*)&lds_r[(seg * 8 + q) * 4];  // LDS broadcast
      ab = __fmaf_rn(rv.x, bv.x, ab);
      ab = __fmaf_rn(rv.y, bv.y, ab);
      ab = __fmaf_rn(rv.z, bv.z, ab);
      ab = __fmaf_rn(rv.w, bv.w, ab);
    }
#pragma unroll
    for (int q = 0; q < 8; ++q) cur[q] = nxt[q];
  }
#pragma unroll
  for (int q = 0; q < 8; ++q) {
    float4 bv = cur[q];
    float4 rv = *(const float4*)&lds_r[(120 + q) * 4];
    ab = __fmaf_rn(rv.x, bv.x, ab);
    ab = __fmaf_rn(rv.y, bv.y, ab);
    ab = __fmaf_rn(rv.z, bv.z, ab);
    ab = __fmaf_rn(rv.w, bv.w, ab);
  }
  return ab;
}

// mask storage formats: 0=u8, 1=i32, 2=i64, 3=bf16, 4=f32
__device__ __forceinline__ int mask_at(const void* m, int t, int flag) {
  switch (flag) {
    case 0:  return ((const unsigned char*)m)[t] != 0;
    case 1:  return ((const int*)m)[t] != 0;
    case 2:  return ((const unsigned long long*)m)[t] != 0ull;
    case 3:  return ((const unsigned short*)m)[t] != 0;
    default: return ((const float*)m)[t] != 0.0f;
  }
}

// Detect mask format, count n_valid, build order-preserving compacted list.
__global__ void k_prep(const unsigned char* mask, int* wsi, float* wsf, int* list) {
  __shared__ int s_not01, s_off1, s_offn0, s_odd, s_fm;
  __shared__ int s_cnt[1024];
  int tid = threadIdx.x;
  if (tid == 0) { s_not01 = 0; s_off1 = 0; s_offn0 = 0; s_odd = 0; }
  __syncthreads();
  int l_not01 = 0, l_off1 = 0, l_offn0 = 0, l_odd = 0;
  for (int o = tid; o < BT; o += 1024) {
    unsigned char b = mask[o];
    if (b) {
      if (b > 1) l_not01 = 1;
      int m4 = o & 3;
      if (m4 == 1) l_off1 = 1;
      if (m4) l_offn0 = 1;
      if ((o & 7) >= 4) l_odd = 1;
    }
  }
  if (l_not01) atomicOr(&s_not01, 1);
  if (l_off1)  atomicOr(&s_off1, 1);
  if (l_offn0) atomicOr(&s_offn0, 1);
  if (l_odd)   atomicOr(&s_odd, 1);
  __syncthreads();
  if (tid == 0) {
    int fm;
    if (s_not01)      fm = s_off1 ? 3 : 4;
    else if (s_offn0) fm = 0;
    else if (s_odd)   fm = 1;
    else              fm = 2;
    s_fm = fm; wsi[0] = fm;
    wsf[8] = 0.0f;                       // loss accumulator
    wsf[12] = 0.f; wsf[13] = 0.f; wsf[14] = 0.f; wsf[15] = 0.f;  // b2max
  }
  __syncthreads();
  int fm = s_fm;
  int base = tid * 32, cnt = 0;
  for (int u = 0; u < 32; u++) cnt += mask_at(mask, base + u, fm);
  int val = cnt;
  s_cnt[tid] = val;
  __syncthreads();
#pragma unroll
  for (int off = 1; off < 1024; off <<= 1) {
    int v = (tid >= off) ? s_cnt[tid - off] : 0;
    __syncthreads();
    val += v;
    s_cnt[tid] = val;
    __syncthreads();
  }
  if (tid == 0) wsi[2] = s_cnt[1023];
  int woff = val - cnt;                  // exclusive prefix
  for (int u = 0; u < 32; u++) {
    int t = base + u;
    if (mask_at(mask, t, fm)) list[woff++] = t;
  }
}

// Invalid tokens: x_q row = 0, indices = -1.
__global__ void k_fill(const void* mask, float* out, const int* wsi) {
  int w = threadIdx.x >> 6, lane = threadIdx.x & 63;
  int t = blockIdx.x * 4 + w;
  if (t >= BT) return;
  if (mask_at(mask, t, wsi[0])) return;
  float4 z = make_float4(0.f, 0.f, 0.f, 0.f);
  float4* p = (float4*)(out + (size_t)t * CDIM) + lane * 2;
  p[0] = z; p[1] = z;
  if (lane < NQ) out[IDX_BASE + (size_t)t * NQ + lane] = -1.0f;
}

// b2: exact sequential chain; also per-codebook b2max.
__global__ void k_b2(const float* __restrict__ cb, float* __restrict__ b2, float* b2max) {
  __shared__ float st[4][512];
  int w = threadIdx.x >> 6, lane = threadIdx.x & 63;
  int row = blockIdx.x * 4 + w;
  const float4* p = (const float4*)(cb + (size_t)row * CDIM) + lane * 2;
  float4 v0 = p[0], v1 = p[1];
  *(float4*)&st[w][lane * 8] = v0;
  *(float4*)&st[w][lane * 8 + 4] = v1;
  __syncthreads();
  if (threadIdx.x < 4) {
    int r2 = blockIdx.x * 4 + threadIdx.x;
    float s = 0.f;
    for (int c4 = 0; c4 < 128; ++c4) {
      float4 v = *(float4*)&st[threadIdx.x][c4 * 4];
      s = __fadd_rn(s, __fmul_rn(v.x, v.x));
      s = __fadd_rn(s, __fmul_rn(v.y, v.y));
      s = __fadd_rn(s, __fmul_rn(v.z, v.z));
      s = __fadd_rn(s, __fmul_rn(v.w, v.w));
    }
    b2[r2] = s;
    atomicMax((int*)&b2max[r2 >> 10], __float_as_int(s));
  }
}

// cb -> fp16 (RNE), once for all codebooks.
__global__ void k_cvtcb(const float* __restrict__ cb, unsigned short* __restrict__ cbb) {
  size_t i = (size_t)blockIdx.x * blockDim.x + threadIdx.x;
  const float4* s = (const float4*)(cb + i * 8);
  float4 a = s[0], b = s[1];
  uint4 u;
  u.x = f2h(a.x) | (f2h(a.y) << 16);
  u.y = f2h(a.z) | (f2h(a.w) << 16);
  u.z = f2h(b.x) | (f2h(b.y) << 16);
  u.w = f2h(b.z) | (f2h(b.w) << 16);
  *(uint4*)(cbb + i * 8) = u;
}

// rws[t] = x[t]; rbc[j] = fp16(x[t]); a2c[j] = exact sequential chain; zero candcnt.
__global__ __launch_bounds__(256) void k_init(const float* __restrict__ x,
    float* __restrict__ rws, unsigned short* __restrict__ rbc,
    const int* __restrict__ wsi, const int* __restrict__ list,
    float* __restrict__ a2c, int* __restrict__ candcnt) {
  __shared__ float st[8][512];
  int nv = wsi[2];
  int j0 = blockIdx.x * 8;
  int tid = threadIdx.x;
  if (tid < 8) candcnt[j0 + tid] = 0;
  if (j0 >= nv) return;
  int slot = tid >> 5;
  int j = j0 + slot;
  int c0 = (tid & 31) * 16;
  if (j < nv) {
    int t = list[j];
    const float4* src = (const float4*)(x + (size_t)t * CDIM + c0);
    float4* dst = (float4*)(rws + (size_t)t * CDIM + c0);
    float4 v0 = src[0], v1 = src[1], v2 = src[2], v3 = src[3];
    dst[0] = v0; dst[1] = v1; dst[2] = v2; dst[3] = v3;
    *(float4*)&st[slot][c0]      = v0; *(float4*)&st[slot][c0 + 4]  = v1;
    *(float4*)&st[slot][c0 + 8]  = v2; *(float4*)&st[slot][c0 + 12] = v3;
    uint4 u0, u1;
    u0.x = f2h(v0.x) | (f2h(v0.y) << 16); u0.y = f2h(v0.z) | (f2h(v0.w) << 16);
    u0.z = f2h(v1.x) | (f2h(v1.y) << 16); u0.w = f2h(v1.z) | (f2h(v1.w) << 16);
    u1.x = f2h(v2.x) | (f2h(v2.y) << 16); u1.y = f2h(v2.z) | (f2h(v2.w) << 16);
    u1.z = f2h(v3.x) | (f2h(v3.y) << 16); u1.w = f2h(v3.z) | (f2h(v3.w) << 16);
    uint4* bd = (uint4*)(rbc + (size_t)j * CDIM + c0);
    bd[0] = u0; bd[1] = u1;
  }
  __syncthreads();
  if (tid < 8) {
    int jj = j0 + tid;
    if (jj < nv) {
      float s = 0.f;
      for (int c4 = 0; c4 < 128; ++c4) {
        float4 v = *(float4*)&st[tid][c4 * 4];
        s = __fadd_rn(s, __fmul_rn(v.x, v.x));
        s = __fadd_rn(s, __fmul_rn(v.y, v.y));
        s = __fadd_rn(s, __fmul_rn(v.z, v.z));
        s = __fadd_rn(s, __fmul_rn(v.w, v.w));
      }
      a2c[jj] = s;
    }
  }
}

// fp16 MFMA GEMM: M-tile 64 (2048 real blocks, 8/CU -> phases overlap across
// blocks), 24KB LDS, DMA staging + bijective runtime-sized XCD remap.
__global__ __launch_bounds__(256) void k_gemm(const unsigned short* __restrict__ rbc,
    const unsigned short* __restrict__ cbb, const float* __restrict__ b2,
    const float* __restrict__ b2max, const float* __restrict__ a2c,
    const int* __restrict__ wsi, int* __restrict__ candcnt,
    int* __restrict__ candk, float* __restrict__ cands, int ic) {
  __shared__ __align__(16) unsigned short As[64 * 64];
  __shared__ __align__(16) unsigned short Bs[128 * 64];
  int nv = wsi[2];
  int nmb = (nv + 63) >> 6;             // real mb count (M-tile = 64)
  int q = blockIdx.x >> 3, x = blockIdx.x & 7;
  if (q >= nmb) return;                 // balanced early-exit across XCDs
  int r = x * nmb + q;                  // bijective: XCD x owns works x*nmb..
  int mb = r >> 3, nb = r & 7;
  int m0 = mb * 64;
  if (m0 >= nv) return;
  int tid = threadIdx.x;
  int w = tid >> 6, lane = tid & 63;
  int wm = w >> 1, wn = w & 1;
  f32x4 acc[2][4];
#pragma unroll
  for (int a = 0; a < 2; a++)
#pragma unroll
    for (int b = 0; b < 4; b++) acc[a][b] = (f32x4){0.f, 0.f, 0.f, 0.f};

  const unsigned short* Ag = rbc + (size_t)m0 * CDIM;
  const unsigned short* Bg = cbb + (size_t)(ic * KCB + nb * 128) * CDIM;
  int w4 = __builtin_amdgcn_readfirstlane(w);   // wave id, scalar
  int lr8 = lane >> 3, lck = lane & 7;
  int l15 = lane & 15, l4 = lane >> 4;

  for (int kc = 0; kc < 8; ++kc) {
    __syncthreads();                    // prev iteration's reads complete
#pragma unroll
    for (int i = 0; i < 2; ++i) {       // A: 64 rows, 16/wave
      int ra = w4 * 16 + i * 8 + lr8;
      int sc = (lck ^ (ra & 7)) << 3;
      const unsigned short* sa = Ag + (size_t)ra * CDIM + kc * 64 + sc;
      __builtin_amdgcn_global_load_lds(
          (const __attribute__((address_space(1))) unsigned int*)sa,
          (__attribute__((address_space(3))) unsigned int*)&As[(w4 * 16 + i * 8) * 64],
          16, 0, 0);
    }
#pragma unroll
    for (int i = 0; i < 4; ++i) {       // B: 128 rows, 32/wave
      int rb_ = w4 * 32 + i * 8 + lr8;
      int sc = (lck ^ (rb_ & 7)) << 3;
      const unsigned short* sb = Bg + (size_t)rb_ * CDIM + kc * 64 + sc;
      __builtin_amdgcn_global_load_lds(
          (const __attribute__((address_space(1))) unsigned int*)sb,
          (__attribute__((address_space(3))) unsigned int*)&Bs[(w4 * 32 + i * 8) * 64],
          16, 0, 0);
    }
    asm volatile("s_waitcnt vmcnt(0)" ::: "memory");
    __syncthreads();
#pragma unroll
    for (int h = 0; h < 2; ++h) {
      f16x8 af[2], bf[4];
#pragma unroll
      for (int mf = 0; mf < 2; ++mf) {
        int row = wm * 32 + mf * 16 + l15;
        af[mf] = *(const f16x8*)&As[row * 64 + (((h * 4 + l4) ^ (row & 7)) << 3)];
      }
#pragma unroll
      for (int nf = 0; nf < 4; ++nf) {
        int row = wn * 64 + nf * 16 + l15;
        bf[nf] = *(const f16x8*)&Bs[row * 64 + (((h * 4 + l4) ^ (row & 7)) << 3)];
      }
#pragma unroll
      for (int mf = 0; mf < 2; ++mf)
#pragma unroll
        for (int nf = 0; nf < 4; ++nf)
          acc[mf][nf] = __builtin_amdgcn_mfma_f32_16x16x32_f16(af[mf], bf[nf], acc[mf][nf], 0, 0, 0);
    }
  }

  const float* b2p = b2 + ic * KCB;
  float bmax = b2max[ic];
#pragma unroll
  for (int mf = 0; mf < 2; ++mf) {
    float sv[4][4];
    int kg[4];
    float smin[4]; int kmin[4];
#pragma unroll
    for (int q2 = 0; q2 < 4; ++q2) { smin[q2] = __builtin_inff(); kmin[q2] = 0; }
#pragma unroll
    for (int nf = 0; nf < 4; ++nf) {
      int k = nb * 128 + wn * 64 + nf * 16 + l15;
      kg[nf] = k;
      float b2k = b2p[k];
#pragma unroll
      for (int q2 = 0; q2 < 4; ++q2) {
        float s = __fsub_rn(b2k, __fmul_rn(2.0f, acc[mf][nf][q2]));
        sv[nf][q2] = s;
        if (s < smin[q2]) { smin[q2] = s; kmin[q2] = k; }
      }
    }
#pragma unroll
    for (int d = 1; d < 16; d <<= 1) {
#pragma unroll
      for (int q2 = 0; q2 < 4; ++q2) {
        float vo = __shfl_xor(smin[q2], d, 64);
        int ko = __shfl_xor(kmin[q2], d, 64);
        if (vo < smin[q2] || (vo == smin[q2] && ko < kmin[q2])) { smin[q2] = vo; kmin[q2] = ko; }
      }
    }
#pragma unroll
    for (int q2 = 0; q2 < 4; ++q2) {
      int j = m0 + wm * 32 + mf * 16 + l4 * 4 + q2;
      if (j < nv) {
        float thr = smin[q2] + MARGIN_C * sqrtf(a2c[j] * bmax) + MARGIN_A;
#pragma unroll
        for (int nf = 0; nf < 4; ++nf) {
          if (sv[nf][q2] <= thr) {
            int pos = atomicAdd(&candcnt[j], 1);
            if (pos < CAND_MAX) {
              candk[(size_t)j * CAND_MAX + pos] = kg[nf];
              cands[(size_t)j * CAND_MAX + pos] = sv[nf][q2];
            }
          }
        }
      }
    }
  }
}

// Argmin only. One token per wave. nk==1 (~93% with fp16 margin) -> free.
__global__ __launch_bounds__(256) void k_argmin(const float* __restrict__ cb,
    const float* __restrict__ rws, const int* __restrict__ list,
    const int* __restrict__ wsi, const float* __restrict__ a2c,
    const float* __restrict__ b2, const float* __restrict__ b2max,
    int* __restrict__ candcnt, const int* __restrict__ candk,
    const float* __restrict__ cands, float* __restrict__ out,
    int* __restrict__ idxsel, int ic) {
  __shared__ float rbuf[4][512];
  int nv = wsi[2];
  int tid = threadIdx.x, wv = tid >> 6, lane = tid & 63;
  int j = blockIdx.x * 4 + wv;
  if (j >= nv) return;                 // per-wave exit; no block barriers
  int t = __builtin_amdgcn_readfirstlane(list[j]);
  int cnt = candcnt[j];
  if (lane == 0) candcnt[j] = 0;       // reset for next codebook
  float a2v = a2c[j];
  const float* b2p = b2 + ic * KCB;
  const float* cbp = cb + (size_t)ic * KCB * CDIM;

  int kw;
  if (cnt <= CAND_MAX) {
    float sa = __builtin_inff(); int kl = 0;
    if (lane < cnt) {
      sa = cands[(size_t)j * CAND_MAX + lane];
      kl = candk[(size_t)j * CAND_MAX + lane];
    }
    float g = sa;
#pragma unroll
    for (int d = 1; d < 64; d <<= 1) g = fminf(g, __shfl_xor(g, d, 64));
    float M = MARGIN_C * sqrtf(a2v * b2max[ic]) + MARGIN_A;
    bool keep = (lane < cnt) && (sa <= g + M);
    unsigned long long mkb = __ballot(keep);
    int nk = (int)__popcll(mkb);         // >= 1 always (min survives)
    if (nk == 1) {
      int src = nth_bit(mkb, 0);
      kw = __shfl(kl, src, 64);
    } else {
      const float4* rr = (const float4*)(rws + (size_t)t * CDIM);
      float4 r0 = rr[lane * 2], r1 = rr[lane * 2 + 1];
      *(float4*)&rbuf[wv][lane * 8]     = r0;
      *(float4*)&rbuf[wv][lane * 8 + 4] = r1;
      int sel = lane % nk;
      int src = nth_bit(mkb, sel);
      int myk = __shfl(kl, src, 64);
      asm volatile("s_waitcnt lgkmcnt(0)" ::: "memory");
      float ab = chain512q(rbuf[wv], cbp + (size_t)myk * CDIM);
      float dv = __fsub_rn(__fadd_rn(a2v, b2p[myk]), __fmul_rn(2.0f, ab));
      int kc = myk;
#pragma unroll
      for (int d = 1; d < 64; d <<= 1) {
        float vo = __shfl_xor(dv, d, 64);
        int ko = __shfl_xor(kc, d, 64);
        if (vo < dv || (vo == dv && ko < kc)) { dv = vo; kc = ko; }
      }
      kw = kc;
    }
  } else {
    // provable fallback: full exact scan, 64 rows per pass (rare)
    const float4* rr = (const float4*)(rws + (size_t)t * CDIM);
    float4 r0 = rr[lane * 2], r1 = rr[lane * 2 + 1];
    *(float4*)&rbuf[wv][lane * 8]     = r0;
    *(float4*)&rbuf[wv][lane * 8 + 4] = r1;
    asm volatile("s_waitcnt lgkmcnt(0)" ::: "memory");
    float dl = __builtin_inff(); int kl2 = 0x7fffffff;
    for (int base = 0; base < KCB; base += 64) {
      int myk = base + lane;
      float ab = chain512q(rbuf[wv], cbp + (size_t)myk * CDIM);
      float dv = __fsub_rn(__fadd_rn(a2v, b2p[myk]), __fmul_rn(2.0f, ab));
      if (dv < dl || (dv == dl && myk < kl2)) { dl = dv; kl2 = myk; }
    }
#pragma unroll
    for (int d = 1; d < 64; d <<= 1) {
      float vo = __shfl_xor(dl, d, 64);
      int ko = __shfl_xor(kl2, d, 64);
      if (vo < dl || (vo == dl && ko < kl2)) { dl = vo; kl2 = ko; }
    }
    kw = kl2;
  }
  if (lane == 0) {
    out[IDX_BASE + (size_t)t * NQ + ic] = (float)kw;
    idxsel[j] = kw;
  }
}

// Streaming exact residual update (k_init-shaped): 8 tokens/block.
__global__ __launch_bounds__(256) void k_upd2(const float* __restrict__ x,
    const float* __restrict__ cb, float* __restrict__ rws,
    unsigned short* __restrict__ rbc, const int* __restrict__ list,
    const int* __restrict__ wsi, float* __restrict__ a2c,
    const int* __restrict__ idxsel, float* __restrict__ lossacc, int ic) {
  __shared__ float st[8][512];
  __shared__ float s_l[4];
  int nv = wsi[2];
  int j0 = blockIdx.x * 8;
  if (j0 >= nv) return;
  int tid = threadIdx.x;
  int slot = tid >> 5;
  int j = j0 + slot;
  bool valid = (j < nv);
  int jc = valid ? j : (nv - 1);
  int t = list[jc];
  int kw = idxsel[jc];
  int c0 = (tid & 31) * 16;
  const float* cbp = cb + (size_t)ic * KCB * CDIM;
  float lsum = 0.f;
  if (valid) {
    float4* rp = (float4*)(rws + (size_t)t * CDIM + c0);
    const float4* qp = (const float4*)(cbp + (size_t)kw * CDIM + c0);
#pragma unroll
    for (int q4 = 0; q4 < 4; ++q4) {
      float4 rv = rp[q4], qv = qp[q4];
      float4 d, n;
      d.x = __fsub_rn(qv.x, rv.x); d.y = __fsub_rn(qv.y, rv.y);
      d.z = __fsub_rn(qv.z, rv.z); d.w = __fsub_rn(qv.w, rv.w);
      n.x = __fsub_rn(rv.x, __fadd_rn(rv.x, d.x));
      n.y = __fsub_rn(rv.y, __fadd_rn(rv.y, d.y));
      n.z = __fsub_rn(rv.z, __fadd_rn(rv.z, d.z));
      n.w = __fsub_rn(rv.w, __fadd_rn(rv.w, d.w));
      lsum = __fmaf_rn(d.x, d.x, lsum); lsum = __fmaf_rn(d.y, d.y, lsum);
      lsum = __fmaf_rn(d.z, d.z, lsum); lsum = __fmaf_rn(d.w, d.w, lsum);
      if (ic < 3) {
        rp[q4] = n;
        *(float4*)&st[slot][c0 + q4 * 4] = n;
        uint2 u;
        u.x = f2h(n.x) | (f2h(n.y) << 16);
        u.y = f2h(n.z) | (f2h(n.w) << 16);
        *(uint2*)(rbc + (size_t)j * CDIM + c0 + q4 * 4) = u;
      } else {
        float4 xv = ((const float4*)(x + (size_t)t * CDIM + c0))[q4];
        float4 o;
        o.x = __fsub_rn(xv.x, n.x); o.y = __fsub_rn(xv.y, n.y);
        o.z = __fsub_rn(xv.z, n.z); o.w = __fsub_rn(xv.w, n.w);
        rp[q4] = o;                 // rws row == out x_q row
      }
    }
  }
  // loss: wave reduce -> LDS -> one atomic
#pragma unroll
  for (int d = 1; d < 64; d <<= 1) lsum += __shfl_xor(lsum, d, 64);
  if ((tid & 63) == 0) s_l[tid >> 6] = lsum;
  __syncthreads();
  if (ic < 3 && tid < 8) {
    int jj = j0 + tid;
    if (jj < nv) {
      float s = 0.f;
      for (int c4 = 0; c4 < 128; ++c4) {
        float4 v = *(float4*)&st[tid][c4 * 4];
        s = __fadd_rn(s, __fmul_rn(v.x, v.x));
        s = __fadd_rn(s, __fmul_rn(v.y, v.y));
        s = __fadd_rn(s, __fmul_rn(v.z, v.z));
        s = __fadd_rn(s, __fmul_rn(v.w, v.w));
      }
      a2c[jj] = s;
    }
  }
  if (tid == 0) atomicAdd(lossacc, (s_l[0] + s_l[1]) + (s_l[2] + s_l[3]));
}

__global__ void k_loss(const int* wsi, const float* acc, float* out) {
  if (threadIdx.x == 0 && blockIdx.x == 0) {
    float n = (float)wsi[2];
    if (n < 1.0f) n = 1.0f;
    out[LOSS_OFF] = acc[0] * 1.25f / (n * (float)CDIM);
  }
}

extern "C" void kernel_launch(void* const* d_in, const int* in_sizes, int n_in,
                              void* d_out, int out_size, void* d_ws, size_t ws_size,
                              hipStream_t stream) {
  const float* x   = (const float*)d_in[0];
  const void* mask = d_in[1];
  const float* cb  = (const float*)d_in[2];
  float* out = (float*)d_out;
  char* ws = (char*)d_ws;
  int*   wsi  = (int*)ws;
  float* wsf  = (float*)ws;
  int*   list = (int*)(ws + WS_LIST);
  float* a2c  = (float*)(ws + WS_A2);
  float* b2   = (float*)(ws + WS_B2);
  unsigned short* rbc = (unsigned short*)(ws + WS_RBC);
  unsigned short* cbb = (unsigned short*)(ws + WS_CBB);
  int*   ccnt = (int*)(ws + WS_CCNT);
  int*   ck   = (int*)(ws + WS_CANDK);
  float* cs   = (float*)(ws + WS_CANDS);
  int*   isel = (int*)(ws + WS_IDXS);
  float* rws  = out;            // x_q region doubles as residual ws (token rows)
  float* b2mx = wsf + 12;

  hipLaunchKernelGGL(k_prep, dim3(1), dim3(1024), 0, stream,
                     (const unsigned char*)mask, wsi, wsf, list);
  hipLaunchKernelGGL(k_fill, dim3(BT / 4), dim3(256), 0, stream, mask, out, wsi);
  hipLaunchKernelGGL(k_b2, dim3(NQ * KCB / 4), dim3(256), 0, stream, cb, b2, b2mx);
  hipLaunchKernelGGL(k_cvtcb, dim3(NQ * KCB * CDIM / 8 / 256), dim3(256), 0, stream, cb, cbb);
  hipLaunchKernelGGL(k_init, dim3(BT / 8), dim3(256), 0, stream,
                     x, rws, rbc, wsi, list, a2c, ccnt);
  for (int ic = 0; ic < NQ; ic++) {
    hipLaunchKernelGGL(k_gemm, dim3((BT / 64) * 8), dim3(256), 0, stream,
                       rbc, cbb, b2, b2mx, a2c, wsi, ccnt, ck, cs, ic);
    hipLaunchKernelGGL(k_argmin, dim3(BT / 4), dim3(256), 0, stream,
                       cb, rws, list, wsi, a2c, b2, b2mx, ccnt, ck, cs,
                       out, isel, ic);
    hipLaunchKernelGGL(k_upd2, dim3(BT / 8), dim3(256), 0, stream,
                       x, cb, rws, rbc, list, wsi, a2c, isel, wsf + 8, ic);
  }
  hipLaunchKernelGGL(k_loss, dim3(1), dim3(1), 0, stream, wsi, wsf + 8, out);
}